// Round 4
// baseline (568.736 us; speedup 1.0000x reference)
//
#include <hip/hip_runtime.h>
#include <hip/hip_bf16.h>
#include <math.h>

#define BB 32
#define SS 4096
#define DMEM 512
#define DATT 512

typedef short short8 __attribute__((ext_vector_type(8)));
typedef short short4v __attribute__((ext_vector_type(4)));
typedef float floatx4 __attribute__((ext_vector_type(4)));

__device__ inline short f2bf(float x) {
    unsigned u = __float_as_uint(x);
    unsigned r = (u + 0x7fffu + ((u >> 16) & 1u)) >> 16;
    return (short)(r & 0xffffu);
}

__device__ inline float fast_tanh(float x) {
    float e = __expf(2.0f * x);
    return 1.0f - 2.0f / (e + 1.0f);
}

// async 16B global->LDS DMA; lds base wave-uniform, HW adds lane*16.
__device__ inline void gld_lds16(const void* g, void* l) {
    __builtin_amdgcn_global_load_lds(
        (const __attribute__((address_space(1))) unsigned int*)g,
        (__attribute__((address_space(3))) unsigned int*)l, 16, 0, 0);
}

// ---------------- prep kernels ----------------

__global__ __launch_bounds__(256)
void conv_mem_kernel(const float* __restrict__ m, short* __restrict__ o) {
    size_t i = (size_t)blockIdx.x * 256 + threadIdx.x;
    const float4* p = (const float4*)m + i * 2;
    float4 a = p[0], b = p[1];
    short8 s;
    s[0] = f2bf(a.x); s[1] = f2bf(a.y); s[2] = f2bf(a.z); s[3] = f2bf(a.w);
    s[4] = f2bf(b.x); s[5] = f2bf(b.y); s[6] = f2bf(b.z); s[7] = f2bf(b.w);
    *((short8*)o + i) = s;
}

__global__ void prep_wt_kernel(const float* __restrict__ Wm, short* __restrict__ Wt) {
    const int n0 = blockIdx.x * 32;
    const int k0 = blockIdx.y * 32;
    const int t = threadIdx.x;
    const int r = t >> 5, c = t & 31;
    __shared__ float lds[32 * 33];
#pragma unroll
    for (int j = 0; j < 4; ++j) {
        int kk = r + j * 8;
        lds[kk * 33 + c] = Wm[(size_t)(k0 + kk) * 512 + n0 + c];
    }
    __syncthreads();
#pragma unroll
    for (int j = 0; j < 4; ++j) {
        int nn = r + j * 8;
        Wt[(size_t)(n0 + nn) * 512 + k0 + c] = f2bf(lds[c * 33 + nn]);
    }
}

// h = hidden @ Wh, full-K per thread (no atomics, no pre-zero needed)
__global__ void prep_h_kernel(const float* __restrict__ hidden, const float* __restrict__ Wh,
                              float* __restrict__ h) {
    const int b = blockIdx.x;
    const int n = blockIdx.y * 256 + threadIdx.x;
    float acc = 0.f;
#pragma unroll 8
    for (int k = 0; k < 512; ++k)
        acc += hidden[b * 512 + k] * Wh[(size_t)k * 512 + n];
    h[b * 512 + n] = acc;
}

// ---------------- score: 512-thr m97-structure GEMM + fused epilogue ----------------
// grid (2 nt, 32 st, 32 b), 512 thr = 8 waves (2m x 4n), wave tile 64x64 (4x4 frags).
// LDS rows LDA=64 shorts (128B = 8 chunks of 16B); slot s of row r holds global
// k-chunk (s ^ (r&7)) -- XOR swizzle on the GLOBAL side so LDS stays lane-contiguous
// for global_load_lds; ds_read_b128 frag reads spread 2 lanes/bank-group (free).

__global__ __launch_bounds__(512, 4)
void score_kernel(const short* __restrict__ memB,
                  const float* __restrict__ coverage,
                  const short* __restrict__ Wt,
                  const float* __restrict__ h,
                  const float* __restrict__ Wc,
                  const float* __restrict__ v,
                  float* __restrict__ scoreParts) {
    const int nt = blockIdx.x;
    const int n0 = nt * 256;
    const int s0 = blockIdx.y * 128;
    const int b  = blockIdx.z;
    const int tid = threadIdx.x;
    const int lane = tid & 63;
    const int wave = tid >> 6;
    const int wm = wave & 1;     // m half (0..1)
    const int wn = wave >> 1;    // n quarter (0..3)
    const int col = lane & 15;
    const int q = lane >> 4;

    __shared__ __align__(16) short tileA[128 * 64];   // 16 KB
    __shared__ __align__(16) short tileB[256 * 64];   // 32 KB
    __shared__ float covS[128];
    __shared__ float sred[4][128];

    if (tid < 128) covS[tid] = coverage[(size_t)b * SS + s0 + tid];

    const char* gA = (const char*)(memB + ((size_t)b * SS + s0) * 512);
    const char* gB = (const char*)(Wt + (size_t)n0 * 512);
    char* ldsA = (char*)tileA + wave * 1024;   // wave-uniform DMA bases
    char* ldsB = (char*)tileB + wave * 1024;

    floatx4 acc[4][4];
#pragma unroll
    for (int mi = 0; mi < 4; ++mi)
#pragma unroll
        for (int ni = 0; ni < 4; ++ni)
            acc[mi][ni] = (floatx4){0.f, 0.f, 0.f, 0.f};

    for (int kt = 0; kt < 8; ++kt) {
        __syncthreads();
        // A: 1024 chunks, 2 insts/thread
#pragma unroll
        for (int it = 0; it < 2; ++it) {
            int ci = it * 512 + tid;
            int row = ci >> 3;
            int gchunk = ((ci & 7) ^ (row & 7)) * 16;
            gld_lds16(gA + (size_t)row * 1024 + kt * 128 + gchunk, ldsA + it * 8192);
        }
        // B: 2048 chunks, 4 insts/thread
#pragma unroll
        for (int it = 0; it < 4; ++it) {
            int ci = it * 512 + tid;
            int row = ci >> 3;
            int gchunk = ((ci & 7) ^ (row & 7)) * 16;
            gld_lds16(gB + (size_t)row * 1024 + kt * 128 + gchunk, ldsB + it * 8192);
        }
        __syncthreads();

#pragma unroll
        for (int ks = 0; ks < 2; ++ks) {
            const int ck = ks * 4 + q;
            const int sw = (ck ^ (col & 7)) * 16;
            short8 af[4], bf[4];
#pragma unroll
            for (int mi = 0; mi < 4; ++mi) {
                int row = wm * 64 + mi * 16 + col;
                af[mi] = *(const short8*)((const char*)tileA + row * 128 + sw);
            }
#pragma unroll
            for (int ni = 0; ni < 4; ++ni) {
                int row = wn * 64 + ni * 16 + col;
                bf[ni] = *(const short8*)((const char*)tileB + row * 128 + sw);
            }
#pragma unroll
            for (int mi = 0; mi < 4; ++mi)
#pragma unroll
                for (int ni = 0; ni < 4; ++ni)
                    acc[mi][ni] = __builtin_amdgcn_mfma_f32_16x16x32_bf16(af[mi], bf[ni], acc[mi][ni], 0, 0, 0);
        }
    }

    // epilogue: score += tanh(m + h + cov*Wc) * v, reduce over n
    float hv[4], wcv[4], vv[4];
#pragma unroll
    for (int ni = 0; ni < 4; ++ni) {
        int n = n0 + wn * 64 + ni * 16 + col;
        hv[ni] = h[b * 512 + n];
        wcv[ni] = Wc[n];
        vv[ni] = v[n];
    }
    float rowAcc[4][4];
#pragma unroll
    for (int mi = 0; mi < 4; ++mi)
#pragma unroll
        for (int r = 0; r < 4; ++r)
            rowAcc[mi][r] = 0.f;
#pragma unroll
    for (int mi = 0; mi < 4; ++mi) {
#pragma unroll
        for (int r = 0; r < 4; ++r) {
            float cv = covS[wm * 64 + mi * 16 + q * 4 + r];
#pragma unroll
            for (int ni = 0; ni < 4; ++ni) {
                float val = acc[mi][ni][r] + hv[ni] + cv * wcv[ni];
                rowAcc[mi][r] += fast_tanh(val) * vv[ni];
            }
        }
    }
#pragma unroll
    for (int off = 1; off < 16; off <<= 1)
#pragma unroll
        for (int mi = 0; mi < 4; ++mi)
#pragma unroll
            for (int r = 0; r < 4; ++r)
                rowAcc[mi][r] += __shfl_xor(rowAcc[mi][r], off, 64);

    if (col == 0) {
#pragma unroll
        for (int mi = 0; mi < 4; ++mi)
#pragma unroll
            for (int r = 0; r < 4; ++r)
                sred[wn][wm * 64 + mi * 16 + q * 4 + r] = rowAcc[mi][r];
    }
    __syncthreads();
    if (tid < 128)
        scoreParts[(size_t)nt * BB * SS + (size_t)b * SS + s0 + tid] =
            sred[0][tid] + sred[1][tid] + sred[2][tid] + sred[3][tid];
}

// ---------------- fallback score (fp32 staging, atomic into scoreParts[0]) ----------------
#define LDAF 72
__global__ __launch_bounds__(256, 2)
void score_fallback(const float* __restrict__ memory,
                    const float* __restrict__ coverage,
                    const short* __restrict__ Wt,
                    const float* __restrict__ h,
                    const float* __restrict__ Wc,
                    const float* __restrict__ v,
                    float* __restrict__ scoreParts) {
    const int n0 = blockIdx.x * 128;
    const int s0 = blockIdx.y * 128;
    const int b  = blockIdx.z;
    const int tid = threadIdx.x;
    const int lane = tid & 63;
    const int wave = tid >> 6;
    const int wm = wave & 1;
    const int wn = wave >> 1;
    const int col = lane & 15;
    const int q = lane >> 4;

    __shared__ __align__(16) short tileA[128 * LDAF];
    __shared__ __align__(16) short tileB[128 * LDAF];
    __shared__ float covS[128];
    __shared__ float sred[2][128];

    if (tid < 128) covS[tid] = coverage[(size_t)b * SS + s0 + tid];

    floatx4 acc[4][4];
#pragma unroll
    for (int mi = 0; mi < 4; ++mi)
#pragma unroll
        for (int ni = 0; ni < 4; ++ni)
            acc[mi][ni] = (floatx4){0.f, 0.f, 0.f, 0.f};

    const float4* gA = (const float4*)(memory + ((size_t)b * SS + s0) * DMEM);
    const short*  gB = Wt + (size_t)n0 * 512;

    for (int kt = 0; kt < 8; ++kt) {
        __syncthreads();
#pragma unroll
        for (int it = 0; it < 8; ++it) {
            int i = tid + it * 256;
            int row = i >> 4, c4 = i & 15;
            float4 f = gA[row * 128 + kt * 16 + c4];
            short4v sv;
            sv.x = f2bf(f.x); sv.y = f2bf(f.y); sv.z = f2bf(f.z); sv.w = f2bf(f.w);
            *(short4v*)&tileA[row * LDAF + c4 * 4] = sv;
        }
#pragma unroll
        for (int it = 0; it < 4; ++it) {
            int i = tid + it * 256;
            int row = i >> 3, g = i & 7;
            short8 s = *(const short8*)(gB + (size_t)row * 512 + kt * 64 + g * 8);
            *(short8*)&tileB[row * LDAF + g * 8] = s;
        }
        __syncthreads();
#pragma unroll
        for (int ks = 0; ks < 2; ++ks) {
            short8 af[4], bf[4];
#pragma unroll
            for (int mi = 0; mi < 4; ++mi)
                af[mi] = *(const short8*)&tileA[(wm * 64 + mi * 16 + col) * LDAF + ks * 32 + q * 8];
#pragma unroll
            for (int ni = 0; ni < 4; ++ni)
                bf[ni] = *(const short8*)&tileB[(wn * 64 + ni * 16 + col) * LDAF + ks * 32 + q * 8];
#pragma unroll
            for (int mi = 0; mi < 4; ++mi)
#pragma unroll
                for (int ni = 0; ni < 4; ++ni)
                    acc[mi][ni] = __builtin_amdgcn_mfma_f32_16x16x32_bf16(af[mi], bf[ni], acc[mi][ni], 0, 0, 0);
        }
    }

    float hv[4], wcv[4], vv[4];
#pragma unroll
    for (int ni = 0; ni < 4; ++ni) {
        int n = n0 + wn * 64 + ni * 16 + col;
        hv[ni] = h[b * 512 + n];
        wcv[ni] = Wc[n];
        vv[ni] = v[n];
    }
    float rowAcc[4][4];
#pragma unroll
    for (int mi = 0; mi < 4; ++mi)
#pragma unroll
        for (int r = 0; r < 4; ++r)
            rowAcc[mi][r] = 0.f;
#pragma unroll
    for (int mi = 0; mi < 4; ++mi)
#pragma unroll
        for (int r = 0; r < 4; ++r) {
            float cv = covS[wm * 64 + mi * 16 + q * 4 + r];
#pragma unroll
            for (int ni = 0; ni < 4; ++ni) {
                float val = acc[mi][ni][r] + hv[ni] + cv * wcv[ni];
                rowAcc[mi][r] += fast_tanh(val) * vv[ni];
            }
        }
#pragma unroll
    for (int off = 1; off < 16; off <<= 1)
#pragma unroll
        for (int mi = 0; mi < 4; ++mi)
#pragma unroll
            for (int r = 0; r < 4; ++r)
                rowAcc[mi][r] += __shfl_xor(rowAcc[mi][r], off, 64);
    if (col == 0)
#pragma unroll
        for (int mi = 0; mi < 4; ++mi)
#pragma unroll
            for (int r = 0; r < 4; ++r)
                sred[wn][wm * 64 + mi * 16 + q * 4 + r] = rowAcc[mi][r];
    __syncthreads();
    if (tid < 128)
        atomicAdd(&scoreParts[(size_t)b * SS + s0 + tid], sred[0][tid] + sred[1][tid]);
}

// ---------------- softmax (sums the 2 score parts) ----------------
__global__ void softmax_kernel(const float* __restrict__ scoreParts,
                               const unsigned char* __restrict__ pad,
                               float* __restrict__ attn_out) {
    const int b = blockIdx.x;
    const int tid = threadIdx.x;  // 1024
    const int wave = tid >> 6, lane = tid & 63;
    __shared__ float redMax[16];
    __shared__ float redSum[16];

    float vals[4];
    float mx = -INFINITY;
#pragma unroll
    for (int i = 0; i < 4; ++i) {
        size_t idx = (size_t)b * SS + tid + i * 1024;
        float s = scoreParts[idx] + scoreParts[(size_t)BB * SS + idx];
        if (pad[idx]) s = -INFINITY;
        vals[i] = s;
        mx = fmaxf(mx, s);
    }
#pragma unroll
    for (int off = 32; off >= 1; off >>= 1) mx = fmaxf(mx, __shfl_xor(mx, off, 64));
    if (lane == 0) redMax[wave] = mx;
    __syncthreads();
    float gmax = -INFINITY;
#pragma unroll
    for (int w = 0; w < 16; ++w) gmax = fmaxf(gmax, redMax[w]);

    float sum = 0.f;
#pragma unroll
    for (int i = 0; i < 4; ++i) {
        float e = __expf(vals[i] - gmax);
        vals[i] = e;
        sum += e;
    }
#pragma unroll
    for (int off = 32; off >= 1; off >>= 1) sum += __shfl_xor(sum, off, 64);
    if (lane == 0) redSum[wave] = sum;
    __syncthreads();
    float gsum = 0.f;
#pragma unroll
    for (int w = 0; w < 16; ++w) gsum += redSum[w];
    const float inv = 1.0f / gsum;
#pragma unroll
    for (int i = 0; i < 4; ++i)
        attn_out[(size_t)b * SS + tid + i * 1024] = vals[i] * inv;
}

// ---------------- context ----------------
__global__ __launch_bounds__(256)
void context_kernel(const float* __restrict__ memory,
                    const float* __restrict__ attn,
                    float* __restrict__ ctx) {
    const int sc = blockIdx.x;
    const int dh = blockIdx.y;
    const int b  = blockIdx.z;
    const int t = threadIdx.x;
    const int c = t & 63;
    const int r = t >> 6;

    __shared__ float wS[128];
    __shared__ float4 red[3][64];

    if (t < 128) wS[t] = attn[(size_t)b * SS + sc * 128 + t];
    __syncthreads();

    const float4* m4 = (const float4*)(memory + ((size_t)b * SS + sc * 128) * DMEM) + dh * 64 + c;
    float4 acc = {0.f, 0.f, 0.f, 0.f};
#pragma unroll 8
    for (int i = 0; i < 32; ++i) {
        int row = i * 4 + r;
        float w = wS[row];
        float4 f = m4[(size_t)row * 128];
        acc.x += w * f.x; acc.y += w * f.y; acc.z += w * f.z; acc.w += w * f.w;
    }
    if (r > 0) red[r - 1][c] = acc;
    __syncthreads();
    if (r == 0) {
#pragma unroll
        for (int j = 0; j < 3; ++j) {
            float4 o = red[j][c];
            acc.x += o.x; acc.y += o.y; acc.z += o.z; acc.w += o.w;
        }
        float* dst = &ctx[b * 512 + dh * 256 + c * 4];
        atomicAdd(dst + 0, acc.x);
        atomicAdd(dst + 1, acc.y);
        atomicAdd(dst + 2, acc.z);
        atomicAdd(dst + 3, acc.w);
    }
}

// ---------------- launch ----------------
extern "C" void kernel_launch(void* const* d_in, const int* in_sizes, int n_in,
                              void* d_out, int out_size, void* d_ws, size_t ws_size,
                              hipStream_t stream) {
    (void)in_sizes; (void)n_in; (void)out_size;
    const float* hidden   = (const float*)d_in[0];
    const float* memory   = (const float*)d_in[1];
    const unsigned char* mem_pad = (const unsigned char*)d_in[2];
    const float* coverage = (const float*)d_in[3];
    const float* Wh       = (const float*)d_in[4];
    const float* Wm       = (const float*)d_in[5];
    const float* Wc       = (const float*)d_in[6];
    const float* v        = (const float*)d_in[7];

    const size_t memB_bytes = (size_t)BB * SS * DMEM * 2;  // 128 MB
    const size_t parts_bytes = (size_t)2 * BB * SS * sizeof(float);  // 1 MB
    const size_t need = memB_bytes + 512 * 1024 + 64 * 1024 + parts_bytes;
    char* ws = (char*)d_ws;

    float* ctx  = (float*)d_out;
    float* attn = (float*)d_out + BB * 512;

    hipMemsetAsync(ctx, 0, BB * 512 * sizeof(float), stream);

    if (ws_size >= need) {
        short* memB  = (short*)ws;
        short* Wt    = (short*)(ws + memB_bytes);
        float* h     = (float*)(ws + memB_bytes + 512 * 1024);
        float* parts = (float*)(ws + memB_bytes + 576 * 1024);

        conv_mem_kernel<<<dim3(BB * SS * DMEM / 8 / 256), dim3(256), 0, stream>>>(memory, memB);
        prep_wt_kernel<<<dim3(16, 16), dim3(256), 0, stream>>>(Wm, Wt);
        prep_h_kernel<<<dim3(32, 2), dim3(256), 0, stream>>>(hidden, Wh, h);
        score_kernel<<<dim3(2, 32, 32), dim3(512), 0, stream>>>(memB, coverage, Wt, h, Wc, v, parts);
        softmax_kernel<<<dim3(BB), dim3(1024), 0, stream>>>(parts, mem_pad, attn);
        context_kernel<<<dim3(32, 2, BB), dim3(256), 0, stream>>>(memory, attn, ctx);
    } else {
        short* Wt    = (short*)ws;
        float* h     = (float*)(ws + 512 * 1024);
        float* parts = (float*)(ws + 576 * 1024);

        hipMemsetAsync(parts, 0, parts_bytes, stream);
        prep_wt_kernel<<<dim3(16, 16), dim3(256), 0, stream>>>(Wm, Wt);
        prep_h_kernel<<<dim3(32, 2), dim3(256), 0, stream>>>(hidden, Wh, h);
        score_fallback<<<dim3(4, 32, 32), dim3(256), 0, stream>>>(memory, coverage, Wt, h, Wc, v, parts);
        softmax_kernel<<<dim3(BB), dim3(1024), 0, stream>>>(parts, mem_pad, attn);
        context_kernel<<<dim3(32, 2, BB), dim3(256), 0, stream>>>(memory, attn, ctx);
    }
}

// Round 5
// 498.025 us; speedup vs baseline: 1.1420x; 1.1420x over previous
//
#include <hip/hip_runtime.h>
#include <hip/hip_bf16.h>
#include <math.h>

#define BB 32
#define SS 4096
#define DMEM 512
#define DATT 512

typedef short short8 __attribute__((ext_vector_type(8)));
typedef short short4v __attribute__((ext_vector_type(4)));
typedef float floatx4 __attribute__((ext_vector_type(4)));

__device__ inline short f2bf(float x) {
    unsigned u = __float_as_uint(x);
    unsigned r = (u + 0x7fffu + ((u >> 16) & 1u)) >> 16;
    return (short)(r & 0xffffu);
}

__device__ inline float fast_tanh(float x) {
    float e = __expf(2.0f * x);
    return 1.0f - 2.0f / (e + 1.0f);
}

// pack 8 fp32 -> 8 bf16 (RNE, packed cvt on gfx950 via hip_bf16 header)
__device__ inline short8 cvt8(float4 lo, float4 hi) {
    union { __hip_bfloat162 h2; unsigned u; } a, b, c, d;
    a.h2 = __float22bfloat162_rn(make_float2(lo.x, lo.y));
    b.h2 = __float22bfloat162_rn(make_float2(lo.z, lo.w));
    c.h2 = __float22bfloat162_rn(make_float2(hi.x, hi.y));
    d.h2 = __float22bfloat162_rn(make_float2(hi.z, hi.w));
    union { unsigned u[4]; short8 s; } r;
    r.u[0] = a.u; r.u[1] = b.u; r.u[2] = c.u; r.u[3] = d.u;
    return r.s;
}

// async 16B global->LDS DMA; lds base wave-uniform, HW adds lane*16.
__device__ inline void gld_lds16(const void* g, void* l) {
    __builtin_amdgcn_global_load_lds(
        (const __attribute__((address_space(1))) unsigned int*)g,
        (__attribute__((address_space(3))) unsigned int*)l, 16, 0, 0);
}

// ---------------- prep kernels ----------------

__global__ void prep_wt_kernel(const float* __restrict__ Wm, short* __restrict__ Wt) {
    const int n0 = blockIdx.x * 32;
    const int k0 = blockIdx.y * 32;
    const int t = threadIdx.x;
    const int r = t >> 5, c = t & 31;
    __shared__ float lds[32 * 33];
#pragma unroll
    for (int j = 0; j < 4; ++j) {
        int kk = r + j * 8;
        lds[kk * 33 + c] = Wm[(size_t)(k0 + kk) * 512 + n0 + c];
    }
    __syncthreads();
#pragma unroll
    for (int j = 0; j < 4; ++j) {
        int nn = r + j * 8;
        Wt[(size_t)(n0 + nn) * 512 + k0 + c] = f2bf(lds[c * 33 + nn]);
    }
}

// h = hidden @ Wh, k-split x4, atomic combine (h pre-zeroed)
__global__ void prep_h_kernel(const float* __restrict__ hidden, const float* __restrict__ Wh,
                              float* __restrict__ h) {
    const int b = blockIdx.x;
    const int n = blockIdx.y * 256 + threadIdx.x;
    const int kc = blockIdx.z;
    float acc = 0.f;
#pragma unroll 8
    for (int k = kc * 128; k < kc * 128 + 128; ++k)
        acc += hidden[b * 512 + k] * Wh[(size_t)k * 512 + n];
    atomicAdd(&h[b * 512 + n], acc);
}

// ---------------- score: fp32-A DMA + in-reg bf16 convert, m97 structure ----------------
// 1-D grid 4096 = 32b*32st*4nt, decoded so the 4 nt-siblings (same A tile) sit 8
// blocks apart => same XCD slot under round-robin dispatch => A echo-reads hit L2.
// 256 thr = 4 waves (2m x 2n), wave tile 64x64 (4x4 frags).
// A rows: 64 fp32 = 16 chunks of 16B, slot s of row r holds global chunk s^(r&15).
// B rows: 64 bf16 = 8 chunks,          slot s of row r holds global chunk s^(r&7).
// Swizzle applied on the GLOBAL side so LDS stays lane-contiguous for global_load_lds;
// frag ds_read_b128 then lands 2 lanes/bank (free, m136).

__global__ __launch_bounds__(256, 3)
void score_kernel(const float* __restrict__ memory,
                  const float* __restrict__ coverage,
                  const short* __restrict__ Wt,
                  const float* __restrict__ h,
                  const float* __restrict__ Wc,
                  const float* __restrict__ v,
                  float* __restrict__ scoreParts) {
    const int g = blockIdx.x;
    const int inner = g & 7;
    const int nt = (g >> 3) & 3;
    const int stb = (g >> 5) * 8 + inner;  // 0..1023
    const int st = stb & 31;
    const int b = stb >> 5;
    const int n0 = nt * 128;
    const int s0 = st * 128;

    const int tid = threadIdx.x;
    const int lane = tid & 63;
    const int wave = tid >> 6;
    const int wm = wave & 1;
    const int wn = wave >> 1;
    const int col = lane & 15;
    const int q = lane >> 4;

    __shared__ __align__(16) float tileA[128 * 64];   // 32 KB fp32
    __shared__ __align__(16) short tileB[128 * 64];   // 16 KB bf16
    __shared__ float covS[128];
    __shared__ float sred[2][128];

    if (tid < 128) covS[tid] = coverage[(size_t)b * SS + s0 + tid];

    const char* gA = (const char*)(memory + ((size_t)b * SS + s0) * 512);  // row pitch 2048B
    const char* gB = (const char*)(Wt + (size_t)n0 * 512);                 // row pitch 1024B
    char* ldsA = (char*)tileA + wave * 1024;
    char* ldsB = (char*)tileB + wave * 1024;

    floatx4 acc[4][4];
#pragma unroll
    for (int mi = 0; mi < 4; ++mi)
#pragma unroll
        for (int ni = 0; ni < 4; ++ni)
            acc[mi][ni] = (floatx4){0.f, 0.f, 0.f, 0.f};

    for (int kt = 0; kt < 8; ++kt) {
        __syncthreads();
        // A: 2048 chunks (128 rows x 16 slots), 8 insts/thread
#pragma unroll
        for (int it = 0; it < 8; ++it) {
            int ci = it * 256 + tid;
            int row = ci >> 4;
            int gch = (ci & 15) ^ (row & 15);
            gld_lds16(gA + (size_t)row * 2048 + kt * 256 + gch * 16, ldsA + it * 4096);
        }
        // B: 1024 chunks (128 rows x 8 slots), 4 insts/thread
#pragma unroll
        for (int it = 0; it < 4; ++it) {
            int ci = it * 256 + tid;
            int row = ci >> 3;
            int gch = (ci & 7) ^ (row & 7);
            gld_lds16(gB + (size_t)row * 1024 + kt * 128 + gch * 16, ldsB + it * 4096);
        }
        __syncthreads();

#pragma unroll
        for (int ks = 0; ks < 2; ++ks) {
            short8 af[4], bf[4];
            const int ca = ks * 8 + q * 2;       // fp32 chunk pair base (A)
            const int cb = (ks * 4 + q);         // bf16 chunk (B)
#pragma unroll
            for (int mi = 0; mi < 4; ++mi) {
                int row = wm * 64 + mi * 16 + col;
                const float4* pA = (const float4*)tileA + row * 16;
                float4 lo = pA[ca ^ (row & 15)];
                float4 hi = pA[(ca + 1) ^ (row & 15)];
                af[mi] = cvt8(lo, hi);
            }
#pragma unroll
            for (int ni = 0; ni < 4; ++ni) {
                int row = wn * 64 + ni * 16 + col;
                bf[ni] = *(const short8*)((const char*)tileB + row * 128 + ((cb ^ (row & 7)) * 16));
            }
#pragma unroll
            for (int mi = 0; mi < 4; ++mi)
#pragma unroll
                for (int ni = 0; ni < 4; ++ni)
                    acc[mi][ni] = __builtin_amdgcn_mfma_f32_16x16x32_bf16(af[mi], bf[ni], acc[mi][ni], 0, 0, 0);
        }
    }

    // epilogue: score += tanh(m + h + cov*Wc) * v, reduce over n
    float hv[4], wcv[4], vv[4];
#pragma unroll
    for (int ni = 0; ni < 4; ++ni) {
        int n = n0 + wn * 64 + ni * 16 + col;
        hv[ni] = h[b * 512 + n];
        wcv[ni] = Wc[n];
        vv[ni] = v[n];
    }
    float rowAcc[4][4];
#pragma unroll
    for (int mi = 0; mi < 4; ++mi)
#pragma unroll
        for (int r = 0; r < 4; ++r)
            rowAcc[mi][r] = 0.f;
#pragma unroll
    for (int mi = 0; mi < 4; ++mi) {
#pragma unroll
        for (int r = 0; r < 4; ++r) {
            float cv = covS[wm * 64 + mi * 16 + q * 4 + r];
#pragma unroll
            for (int ni = 0; ni < 4; ++ni) {
                float val = acc[mi][ni][r] + hv[ni] + cv * wcv[ni];
                rowAcc[mi][r] += fast_tanh(val) * vv[ni];
            }
        }
    }
#pragma unroll
    for (int off = 1; off < 16; off <<= 1)
#pragma unroll
        for (int mi = 0; mi < 4; ++mi)
#pragma unroll
            for (int r = 0; r < 4; ++r)
                rowAcc[mi][r] += __shfl_xor(rowAcc[mi][r], off, 64);

    if (col == 0) {
#pragma unroll
        for (int mi = 0; mi < 4; ++mi)
#pragma unroll
            for (int r = 0; r < 4; ++r)
                sred[wn][wm * 64 + mi * 16 + q * 4 + r] = rowAcc[mi][r];
    }
    __syncthreads();
    if (tid < 128)
        scoreParts[(size_t)nt * BB * SS + (size_t)b * SS + s0 + tid] =
            sred[0][tid] + sred[1][tid];
}

// ---------------- softmax (sums 4 score parts) ----------------
__global__ void softmax_kernel(const float* __restrict__ scoreParts,
                               const unsigned char* __restrict__ pad,
                               float* __restrict__ attn_out) {
    const int b = blockIdx.x;
    const int tid = threadIdx.x;  // 1024
    const int wave = tid >> 6, lane = tid & 63;
    __shared__ float redMax[16];
    __shared__ float redSum[16];

    float vals[4];
    float mx = -INFINITY;
#pragma unroll
    for (int i = 0; i < 4; ++i) {
        size_t idx = (size_t)b * SS + tid + i * 1024;
        float s = scoreParts[idx] + scoreParts[(size_t)BB * SS + idx]
                + scoreParts[2 * (size_t)BB * SS + idx] + scoreParts[3 * (size_t)BB * SS + idx];
        if (pad[idx]) s = -INFINITY;
        vals[i] = s;
        mx = fmaxf(mx, s);
    }
#pragma unroll
    for (int off = 32; off >= 1; off >>= 1) mx = fmaxf(mx, __shfl_xor(mx, off, 64));
    if (lane == 0) redMax[wave] = mx;
    __syncthreads();
    float gmax = -INFINITY;
#pragma unroll
    for (int w = 0; w < 16; ++w) gmax = fmaxf(gmax, redMax[w]);

    float sum = 0.f;
#pragma unroll
    for (int i = 0; i < 4; ++i) {
        float e = __expf(vals[i] - gmax);
        vals[i] = e;
        sum += e;
    }
#pragma unroll
    for (int off = 32; off >= 1; off >>= 1) sum += __shfl_xor(sum, off, 64);
    if (lane == 0) redSum[wave] = sum;
    __syncthreads();
    float gsum = 0.f;
#pragma unroll
    for (int w = 0; w < 16; ++w) gsum += redSum[w];
    const float inv = 1.0f / gsum;
#pragma unroll
    for (int i = 0; i < 4; ++i)
        attn_out[(size_t)b * SS + tid + i * 1024] = vals[i] * inv;
}

// ---------------- context ----------------
__global__ __launch_bounds__(256)
void context_kernel(const float* __restrict__ memory,
                    const float* __restrict__ attn,
                    float* __restrict__ ctx) {
    const int sc = blockIdx.x;
    const int dh = blockIdx.y;
    const int b  = blockIdx.z;
    const int t = threadIdx.x;
    const int c = t & 63;
    const int r = t >> 6;

    __shared__ float wS[128];
    __shared__ float4 red[3][64];

    if (t < 128) wS[t] = attn[(size_t)b * SS + sc * 128 + t];
    __syncthreads();

    const float4* m4 = (const float4*)(memory + ((size_t)b * SS + sc * 128) * DMEM) + dh * 64 + c;
    float4 acc = {0.f, 0.f, 0.f, 0.f};
#pragma unroll 8
    for (int i = 0; i < 32; ++i) {
        int row = i * 4 + r;
        float w = wS[row];
        float4 f = m4[(size_t)row * 128];
        acc.x += w * f.x; acc.y += w * f.y; acc.z += w * f.z; acc.w += w * f.w;
    }
    if (r > 0) red[r - 1][c] = acc;
    __syncthreads();
    if (r == 0) {
#pragma unroll
        for (int j = 0; j < 3; ++j) {
            float4 o = red[j][c];
            acc.x += o.x; acc.y += o.y; acc.z += o.z; acc.w += o.w;
        }
        float* dst = &ctx[b * 512 + dh * 256 + c * 4];
        atomicAdd(dst + 0, acc.x);
        atomicAdd(dst + 1, acc.y);
        atomicAdd(dst + 2, acc.z);
        atomicAdd(dst + 3, acc.w);
    }
}

// ---------------- launch ----------------
extern "C" void kernel_launch(void* const* d_in, const int* in_sizes, int n_in,
                              void* d_out, int out_size, void* d_ws, size_t ws_size,
                              hipStream_t stream) {
    (void)in_sizes; (void)n_in; (void)out_size; (void)ws_size;
    const float* hidden   = (const float*)d_in[0];
    const float* memory   = (const float*)d_in[1];
    const unsigned char* mem_pad = (const unsigned char*)d_in[2];
    const float* coverage = (const float*)d_in[3];
    const float* Wh       = (const float*)d_in[4];
    const float* Wm       = (const float*)d_in[5];
    const float* Wc       = (const float*)d_in[6];
    const float* v        = (const float*)d_in[7];

    char* ws = (char*)d_ws;
    short* Wt    = (short*)ws;                      // 512 KB
    float* h     = (float*)(ws + 512 * 1024);       // 64 KB
    float* parts = (float*)(ws + 576 * 1024);       // 4 * 512 KB

    float* ctx  = (float*)d_out;
    float* attn = (float*)d_out + BB * 512;

    hipMemsetAsync(ctx, 0, BB * 512 * sizeof(float), stream);
    hipMemsetAsync(h, 0, BB * 512 * sizeof(float), stream);
    prep_wt_kernel<<<dim3(16, 16), dim3(256), 0, stream>>>(Wm, Wt);
    prep_h_kernel<<<dim3(32, 2, 4), dim3(256), 0, stream>>>(hidden, Wh, h);
    score_kernel<<<dim3(4096), dim3(256), 0, stream>>>(memory, coverage, Wt, h, Wc, v, parts);
    softmax_kernel<<<dim3(BB), dim3(1024), 0, stream>>>(parts, mem_pad, attn);
    context_kernel<<<dim3(32, 2, BB), dim3(256), 0, stream>>>(memory, attn, ctx);
}